// Round 15
// baseline (486.520 us; speedup 1.0000x reference)
//
#include <hip/hip_runtime.h>
#include <math.h>

#define FDIM 4096
#define DDIM 256
#define ALPHA_R 0.001f
#define SVH (3 * 32 * 256)

typedef __attribute__((ext_vector_type(8))) short short8;
typedef __attribute__((ext_vector_type(4))) float f32x4;

__device__ __forceinline__ unsigned cvt_pk_bf16(float lo_e, float hi_e) {
  unsigned r;
  asm("v_cvt_pk_bf16_f32 %0, %1, %2" : "=v"(r) : "v"(lo_e), "v"(hi_e));
  return r;
}

// split 8 fp32 -> hi/lo packed uint4s
__device__ __forceinline__ void hilo8(const float* x, uint4& H, uint4& L) {
  unsigned h0 = cvt_pk_bf16(x[0], x[1]);
  unsigned h1 = cvt_pk_bf16(x[2], x[3]);
  unsigned h2 = cvt_pk_bf16(x[4], x[5]);
  unsigned h3 = cvt_pk_bf16(x[6], x[7]);
  unsigned l0 = cvt_pk_bf16(x[0] - __uint_as_float(h0 << 16),
                            x[1] - __uint_as_float(h0 & 0xFFFF0000u));
  unsigned l1 = cvt_pk_bf16(x[2] - __uint_as_float(h1 << 16),
                            x[3] - __uint_as_float(h1 & 0xFFFF0000u));
  unsigned l2 = cvt_pk_bf16(x[4] - __uint_as_float(h2 << 16),
                            x[5] - __uint_as_float(h2 & 0xFFFF0000u));
  unsigned l3 = cvt_pk_bf16(x[6] - __uint_as_float(h3 << 16),
                            x[7] - __uint_as_float(h3 & 0xFFFF0000u));
  H = make_uint4(h0, h1, h2, h3);
  L = make_uint4(l0, l1, l2, l3);
}

// ---- fused: split-F MFMA Gram (blocks 0..1023) + q column-sum (1024..1535) --
// LDS is a single overlaid buffer: colsum's redq aliases the gram staging
// arrays (paths are mutually exclusive) -> 31.8 KB/block -> 5 blocks/CU.
__global__ __launch_bounds__(256) void gram_fused(const float* __restrict__ kg,
                                                  const float* __restrict__ vg,
                                                  const float* __restrict__ qg,
                                                  float* __restrict__ Gp0,
                                                  float* __restrict__ Gp1,
                                                  float* __restrict__ svec,
                                                  float* __restrict__ part) {
  __shared__ __align__(16) char smem[31808];
  int flat = blockIdx.x;            // 1536
  int tid = threadIdx.x;

  if (flat >= 1024) {
    // ---------------- q colsum path (redq aliases smem) ----------------
    float (*redq)[64][4] = (float (*)[64][4])smem;
    int cs = flat - 1024;           // 512 = 16 chunks x 32 batches
    int chunk = cs & 15, b = cs >> 4;
    int rg = tid >> 6, dq = tid & 63;
    const float* p = qg + ((size_t)b * FDIM + chunk * 256 + rg) * DDIM + dq * 4;
    float4 s = make_float4(0.f, 0.f, 0.f, 0.f);
    for (int i = 0; i < 64; ++i) {
      float4 t = *(const float4*)(p + (size_t)i * 4 * DDIM);
      s.x += t.x; s.y += t.y; s.z += t.z; s.w += t.w;
    }
    *(float4*)&redq[rg][dq][0] = s;
    __syncthreads();
    if (rg == 0) {
      float4 a0 = *(float4*)&redq[0][dq][0];
      float4 a1 = *(float4*)&redq[1][dq][0];
      float4 a2 = *(float4*)&redq[2][dq][0];
      float4 a3 = *(float4*)&redq[3][dq][0];
      float4 t = make_float4(a0.x + a1.x + a2.x + a3.x, a0.y + a1.y + a2.y + a3.y,
                             a0.z + a1.z + a2.z + a3.z, a0.w + a1.w + a2.w + a3.w);
      *(float4*)(part + ((size_t)chunk * 32 + b) * DDIM + dq * 4) = t;
    }
    return;
  }

  // ---------------- gram path (1024 blocks = 8 xcd x 4 b x 16 tile x 2 half)
  unsigned short (*Ah)[40] = (unsigned short (*)[40])(smem);
  unsigned short (*Al)[40] = (unsigned short (*)[40])(smem + 5120);
  unsigned short (*Bh)[40] = (unsigned short (*)[40])(smem + 10240);
  unsigned short (*Bl)[40] = (unsigned short (*)[40])(smem + 15360);
  unsigned short (*Ch)[40] = (unsigned short (*)[40])(smem + 20480);
  unsigned short (*Cl)[40] = (unsigned short (*)[40])(smem + 25600);
  float (*sred)[68] = (float (*)[68])(smem + 30720);

  int xcd = flat & 7, s = flat >> 3;
  int b = xcd * 4 + (s >> 5);
  int rem = s & 31;
  int tile = rem >> 1;
  int half = rem & 1;
  int tm = tile >> 2, tn = tile & 3;
  int mBase = tm * 64, nBase = tn * 64;
  const float* Kb = kg + (size_t)b * FDIM * DDIM;
  const float* Vb = vg + (size_t)b * FDIM * DDIM;

  int w = tid >> 6, lane = tid & 63;
  int wr = w >> 1, wc = w & 1;
  int lrow = lane & 15;
  int kof = (lane >> 4) * 8;

  const float* pA = Kb + mBase + lane;
  const float* pB = Kb + nBase + lane;
  const float* pC = Vb + nBase + lane;

  bool doK = (tn == 0), doV = (tm == 0);
  float sK = 0.f, sV = 0.f;
  int fBase = half * 2048;

  float xa[8], xb[8], xc[8];
  auto loadIter = [&](int it) {
    int f = fBase + it * 32 + w * 8;
#pragma unroll
    for (int j = 0; j < 8; ++j) {
      xa[j] = pA[(size_t)(f + j) * DDIM];
      xb[j] = pB[(size_t)(f + j) * DDIM];
      xc[j] = pC[(size_t)(f + j) * DDIM];
    }
  };
  auto stash = [&](const float* x, unsigned short (*H)[40], unsigned short (*L)[40]) {
    uint4 hh, ll;
    hilo8(x, hh, ll);
    *(uint4*)&H[lane][w * 8] = hh;
    *(uint4*)&L[lane][w * 8] = ll;
  };

  f32x4 acc0[2][2], acc1[2][2];
#pragma unroll
  for (int mt = 0; mt < 2; ++mt)
#pragma unroll
    for (int nt = 0; nt < 2; ++nt) {
      acc0[mt][nt] = (f32x4){0.f, 0.f, 0.f, 0.f};
      acc1[mt][nt] = (f32x4){0.f, 0.f, 0.f, 0.f};
    }

  loadIter(0);
  for (int it = 0; it < 64; ++it) {
    __syncthreads();
    stash(xa, Ah, Al);
    stash(xb, Bh, Bl);
    stash(xc, Ch, Cl);
    if (doK) sK += ((xa[0] + xa[1]) + (xa[2] + xa[3])) + ((xa[4] + xa[5]) + (xa[6] + xa[7]));
    if (doV) sV += ((xc[0] + xc[1]) + (xc[2] + xc[3])) + ((xc[4] + xc[5]) + (xc[6] + xc[7]));
    __syncthreads();
    if (it < 63) loadIter(it + 1);

    short8 bh[2], bl[2], ch[2], cl[2];
#pragma unroll
    for (int nt = 0; nt < 2; ++nt) {
      int rB = wc * 32 + nt * 16 + lrow;
      bh[nt] = *(const short8*)&Bh[rB][kof];
      bl[nt] = *(const short8*)&Bl[rB][kof];
      ch[nt] = *(const short8*)&Ch[rB][kof];
      cl[nt] = *(const short8*)&Cl[rB][kof];
    }
    __builtin_amdgcn_s_setprio(1);
#pragma unroll
    for (int mt = 0; mt < 2; ++mt) {
      int rA = wr * 32 + mt * 16 + lrow;
      short8 ah = *(const short8*)&Ah[rA][kof];
      short8 al = *(const short8*)&Al[rA][kof];
#pragma unroll
      for (int nt = 0; nt < 2; ++nt) {
        f32x4 t = acc0[mt][nt];
        t = __builtin_amdgcn_mfma_f32_16x16x32_bf16(ah, bh[nt], t, 0, 0, 0);
        t = __builtin_amdgcn_mfma_f32_16x16x32_bf16(ah, bl[nt], t, 0, 0, 0);
        t = __builtin_amdgcn_mfma_f32_16x16x32_bf16(al, bh[nt], t, 0, 0, 0);
        acc0[mt][nt] = t;
        f32x4 u = acc1[mt][nt];
        u = __builtin_amdgcn_mfma_f32_16x16x32_bf16(ah, ch[nt], u, 0, 0, 0);
        u = __builtin_amdgcn_mfma_f32_16x16x32_bf16(ah, cl[nt], u, 0, 0, 0);
        u = __builtin_amdgcn_mfma_f32_16x16x32_bf16(al, ch[nt], u, 0, 0, 0);
        acc1[mt][nt] = u;
      }
    }
    __builtin_amdgcn_s_setprio(0);
  }

  float* Gp = half ? Gp1 : Gp0;
  float* G0 = Gp + ((size_t)b * 2) * 65536;
  float* G1 = G0 + 65536;
#pragma unroll
  for (int mt = 0; mt < 2; ++mt)
#pragma unroll
    for (int nt = 0; nt < 2; ++nt)
#pragma unroll
      for (int r = 0; r < 4; ++r) {
        int row = mBase + wr * 32 + mt * 16 + (lane >> 4) * 4 + r;
        int col = nBase + wc * 32 + nt * 16 + (lane & 15);
        G0[(size_t)row * DDIM + col] = acc0[mt][nt][r];
        G1[(size_t)row * DDIM + col] = acc1[mt][nt][r];
      }

  float* svecH = svec + (size_t)half * SVH;
  if (doK) {
    __syncthreads();
    sred[w][lane] = sK;
    __syncthreads();
    if (tid < 64) {
      float t = sred[0][tid] + sred[1][tid] + sred[2][tid] + sred[3][tid];
      svecH[(size_t)1 * 32 * 256 + (size_t)b * 256 + mBase + tid] = t;
    }
  }
  if (doV) {
    __syncthreads();
    sred[w][lane] = sV;
    __syncthreads();
    if (tid < 64) {
      float t = sred[0][tid] + sred[1][tid] + sred[2][tid] + sred[3][tid];
      svecH[(size_t)2 * 32 * 256 + (size_t)b * 256 + nBase + tid] = t;
    }
  }
}

// ------- small vectors: sums q-partials + both svec halves ------------------
__global__ void smallvec(const float* __restrict__ Wq, const float* __restrict__ bq,
                         const float* __restrict__ Wk, const float* __restrict__ Wv,
                         const float* __restrict__ part,
                         const float* __restrict__ svec, float* __restrict__ uvec) {
  int b = blockIdx.x; int d = threadIdx.x;
  __shared__ float sq[256], sk[256], sv[256];
  float sqv = 0.f;
  for (int c = 0; c < 16; ++c) sqv += part[((size_t)c * 32 + b) * DDIM + d];
  sq[d] = sqv;
  sk[d] = svec[((size_t)1 * 32 + b) * DDIM + d] + svec[SVH + ((size_t)1 * 32 + b) * DDIM + d];
  sv[d] = svec[((size_t)2 * 32 + b) * DDIM + d] + svec[SVH + ((size_t)2 * 32 + b) * DDIM + d];
  __syncthreads();
  float uk = 0.f, uv = 0.f, uq = 0.f;
  for (int j = 0; j < 256; j += 4) {
    float4 wk4 = *(const float4*)(Wk + (size_t)d * DDIM + j);
    float4 wv4 = *(const float4*)(Wv + (size_t)d * DDIM + j);
    float4 wq4 = *(const float4*)(Wq + (size_t)d * DDIM + j);
    uk += wk4.x * sk[j] + wk4.y * sk[j + 1] + wk4.z * sk[j + 2] + wk4.w * sk[j + 3];
    uv += wv4.x * sv[j] + wv4.y * sv[j + 1] + wv4.z * sv[j + 2] + wv4.w * sv[j + 3];
    uq += wq4.x * sq[j] + wq4.y * sq[j + 1] + wq4.z * sq[j + 2] + wq4.w * sq[j + 3];
  }
  uvec[((size_t)0 * 32 + b) * DDIM + d] = uk;
  uvec[((size_t)1 * 32 + b) * DDIM + d] = uv;
  uvec[((size_t)2 * 32 + b) * DDIM + d] = uq + 4096.f * bq[d];
}

// ------- T[b][w] = Wk @ (Gp0+Gp1)[b][w]  (nn GEMM, MFMA bf16 hi/lo 4-term) --
__global__ __launch_bounds__(256) void gemm_pass1(const float* __restrict__ Wk,
                                                  const float* __restrict__ Gp0,
                                                  const float* __restrict__ Gp1,
                                                  float* __restrict__ T) {
  int tile = blockIdx.x, wsel = blockIdx.y, b = blockIdx.z;
  int tm = tile >> 2, tn = tile & 3;
  int mBase = tm * 64, nBase = tn * 64;
  const float* A = Wk;
  const float* B0 = Gp0 + ((size_t)b * 2 + wsel) * 65536;
  const float* B1 = Gp1 + ((size_t)b * 2 + wsel) * 65536;
  float* C = T + ((size_t)b * 2 + wsel) * 65536;

  __shared__ __align__(16) unsigned short Ah[64][40], Al[64][40];
  __shared__ __align__(16) unsigned short Bh[64][40], Bl[64][40];

  int tid = threadIdx.x;
  int w = tid >> 6, lane = tid & 63;
  int wr = w >> 1, wc = w & 1;
  int lrow = lane & 15;
  int kof = (lane >> 4) * 8;
  int ar = tid >> 2, aq = tid & 3;
  const float* pArow = A + (size_t)(mBase + ar) * DDIM + aq * 8;
  int bw = tid >> 6;
  const float* pB0 = B0 + nBase + lane;
  const float* pB1 = B1 + nBase + lane;

  float xa[8], xb[8];
  auto loadIter = [&](int k0) {
    float4 a0 = *(const float4*)(pArow + k0);
    float4 a1 = *(const float4*)(pArow + k0 + 4);
    xa[0] = a0.x; xa[1] = a0.y; xa[2] = a0.z; xa[3] = a0.w;
    xa[4] = a1.x; xa[5] = a1.y; xa[6] = a1.z; xa[7] = a1.w;
#pragma unroll
    for (int j = 0; j < 8; ++j) {
      size_t o = (size_t)(k0 + bw * 8 + j) * DDIM;
      xb[j] = pB0[o] + pB1[o];
    }
  };

  f32x4 acc[2][2];
#pragma unroll
  for (int mt = 0; mt < 2; ++mt)
#pragma unroll
    for (int nt = 0; nt < 2; ++nt) acc[mt][nt] = (f32x4){0.f, 0.f, 0.f, 0.f};

  loadIter(0);
  for (int it = 0; it < 8; ++it) {
    __syncthreads();
    {
      uint4 hh, ll;
      hilo8(xa, hh, ll);
      *(uint4*)&Ah[ar][aq * 8] = hh;
      *(uint4*)&Al[ar][aq * 8] = ll;
      hilo8(xb, hh, ll);
      *(uint4*)&Bh[lane][bw * 8] = hh;
      *(uint4*)&Bl[lane][bw * 8] = ll;
    }
    __syncthreads();
    if (it < 7) loadIter((it + 1) * 32);

    short8 bh[2], bl[2];
#pragma unroll
    for (int nt = 0; nt < 2; ++nt) {
      int rB = wc * 32 + nt * 16 + lrow;
      bh[nt] = *(const short8*)&Bh[rB][kof];
      bl[nt] = *(const short8*)&Bl[rB][kof];
    }
    __builtin_amdgcn_s_setprio(1);
#pragma unroll
    for (int mt = 0; mt < 2; ++mt) {
      int rA = wr * 32 + mt * 16 + lrow;
      short8 ah = *(const short8*)&Ah[rA][kof];
      short8 al = *(const short8*)&Al[rA][kof];
#pragma unroll
      for (int nt = 0; nt < 2; ++nt) {
        f32x4 t = acc[mt][nt];
        t = __builtin_amdgcn_mfma_f32_16x16x32_bf16(ah, bh[nt], t, 0, 0, 0);
        t = __builtin_amdgcn_mfma_f32_16x16x32_bf16(ah, bl[nt], t, 0, 0, 0);
        t = __builtin_amdgcn_mfma_f32_16x16x32_bf16(al, bh[nt], t, 0, 0, 0);
        t = __builtin_amdgcn_mfma_f32_16x16x32_bf16(al, bl[nt], t, 0, 0, 0);
        acc[mt][nt] = t;
      }
    }
    __builtin_amdgcn_s_setprio(0);
  }

#pragma unroll
  for (int mt = 0; mt < 2; ++mt)
#pragma unroll
    for (int nt = 0; nt < 2; ++nt)
#pragma unroll
      for (int r = 0; r < 4; ++r) {
        int row = mBase + wr * 32 + mt * 16 + (lane >> 4) * 4 + r;
        int col = nBase + wc * 32 + nt * 16 + (lane & 15);
        C[(size_t)row * DDIM + col] = acc[mt][nt][r];
      }
}

// -- S[b][w] = T[b][w] @ W^T + rank1 + alpha*I (nt GEMM, MFMA 4-term) --------
__global__ __launch_bounds__(256) void gemm_pass2(const float* __restrict__ T,
                                                  const float* __restrict__ Wk,
                                                  const float* __restrict__ Wv,
                                                  float* __restrict__ S,
                                                  const float* __restrict__ uvec,
                                                  const float* __restrict__ bk,
                                                  const float* __restrict__ bv) {
  int tile = blockIdx.x, wsel = blockIdx.y, b = blockIdx.z;
  int tm = tile >> 2, tn = tile & 3;
  int mBase = tm * 64, nBase = tn * 64;
  const float* A = T + ((size_t)b * 2 + wsel) * 65536;
  const float* W = wsel ? Wv : Wk;
  float* C = S + ((size_t)b * 2 + wsel) * 65536;

  __shared__ __align__(16) unsigned short Ah[64][40], Al[64][40];
  __shared__ __align__(16) unsigned short Bh[64][40], Bl[64][40];

  int tid = threadIdx.x;
  int w = tid >> 6, lane = tid & 63;
  int wr = w >> 1, wc = w & 1;
  int lrow = lane & 15;
  int kof = (lane >> 4) * 8;
  int ar = tid >> 2, aq = tid & 3;
  const float* pArow = A + (size_t)(mBase + ar) * DDIM + aq * 8;
  const float* pBrow = W + (size_t)(nBase + ar) * DDIM + aq * 8;

  float xa[8], xb[8];
  auto loadIter = [&](int k0) {
    float4 a0 = *(const float4*)(pArow + k0);
    float4 a1 = *(const float4*)(pArow + k0 + 4);
    xa[0] = a0.x; xa[1] = a0.y; xa[2] = a0.z; xa[3] = a0.w;
    xa[4] = a1.x; xa[5] = a1.y; xa[6] = a1.z; xa[7] = a1.w;
    float4 b0 = *(const float4*)(pBrow + k0);
    float4 b1 = *(const float4*)(pBrow + k0 + 4);
    xb[0] = b0.x; xb[1] = b0.y; xb[2] = b0.z; xb[3] = b0.w;
    xb[4] = b1.x; xb[5] = b1.y; xb[6] = b1.z; xb[7] = b1.w;
  };

  f32x4 acc[2][2];
#pragma unroll
  for (int mt = 0; mt < 2; ++mt)
#pragma unroll
    for (int nt = 0; nt < 2; ++nt) acc[mt][nt] = (f32x4){0.f, 0.f, 0.f, 0.f};

  loadIter(0);
  for (int it = 0; it < 8; ++it) {
    __syncthreads();
    {
      uint4 hh, ll;
      hilo8(xa, hh, ll);
      *(uint4*)&Ah[ar][aq * 8] = hh;
      *(uint4*)&Al[ar][aq * 8] = ll;
      hilo8(xb, hh, ll);
      *(uint4*)&Bh[ar][aq * 8] = hh;
      *(uint4*)&Bl[ar][aq * 8] = ll;
    }
    __syncthreads();
    if (it < 7) loadIter((it + 1) * 32);

    short8 bh[2], bl[2];
#pragma unroll
    for (int nt = 0; nt < 2; ++nt) {
      int rB = wc * 32 + nt * 16 + lrow;
      bh[nt] = *(const short8*)&Bh[rB][kof];
      bl[nt] = *(const short8*)&Bl[rB][kof];
    }
    __builtin_amdgcn_s_setprio(1);
#pragma unroll
    for (int mt = 0; mt < 2; ++mt) {
      int rA = wr * 32 + mt * 16 + lrow;
      short8 ah = *(const short8*)&Ah[rA][kof];
      short8 al = *(const short8*)&Al[rA][kof];
#pragma unroll
      for (int nt = 0; nt < 2; ++nt) {
        f32x4 t = acc[mt][nt];
        t = __builtin_amdgcn_mfma_f32_16x16x32_bf16(ah, bh[nt], t, 0, 0, 0);
        t = __builtin_amdgcn_mfma_f32_16x16x32_bf16(ah, bl[nt], t, 0, 0, 0);
        t = __builtin_amdgcn_mfma_f32_16x16x32_bf16(al, bh[nt], t, 0, 0, 0);
        t = __builtin_amdgcn_mfma_f32_16x16x32_bf16(al, bl[nt], t, 0, 0, 0);
        acc[mt][nt] = t;
      }
    }
    __builtin_amdgcn_s_setprio(0);
  }

  // fused rank-1 epilogue
  const float* uk = uvec + ((size_t)0 * 32 + b) * DDIM;
  const float* uvv = uvec + ((size_t)1 * 32 + b) * DDIM;
#pragma unroll
  for (int mt = 0; mt < 2; ++mt)
#pragma unroll
    for (int nt = 0; nt < 2; ++nt) {
      int col = nBase + wc * 32 + nt * 16 + (lane & 15);
      float ue = wsel ? uvv[col] : uk[col];
      float be = wsel ? bv[col] : bk[col];
#pragma unroll
      for (int r = 0; r < 4; ++r) {
        int row = mBase + wr * 32 + mt * 16 + (lane >> 4) * 4 + r;
        float add = uk[row] * be + bk[row] * ue + 4096.f * bk[row] * be;
        if (wsel == 0 && row == col) add += ALPHA_R;
        C[(size_t)row * DDIM + col] = acc[mt][nt][r] + add;
      }
    }
}

// -- gj_factor: R6 structure + 2-pivot look-ahead (pivots 2t,2t+1 per phase;
// consumers reconstruct pivot-row-1 locally: bitwise-identical math).
__global__ __launch_bounds__(1024, 4) void gj_factor(float* __restrict__ Sb,
                                                     float* __restrict__ Mtg) {
  int b = blockIdx.x;
  float* A = Sb + (size_t)b * 2 * 65536;
  int tid = threadIdx.x;
  int r = tid >> 2;
  int q = tid & 3;

  __shared__ __align__(16) float Mt[64][264];
  __shared__ __align__(16) float Sst[64][200];
  __shared__ __align__(16) float prow0[2][64], prow1p[2][64];
  __shared__ float fac0[2][256], fac1p[2][256];

  for (int pg = 0; pg < 4; ++pg) {
    int pg64 = pg * 64;
    float x[16];
    {
      const float* Ar = A + (size_t)r * 256 + pg64 + q * 16;
#pragma unroll
      for (int m = 0; m < 4; ++m) {
        float4 t = *(const float4*)(Ar + m * 4);
        x[m * 4 + 0] = t.x; x[m * 4 + 1] = t.y;
        x[m * 4 + 2] = t.z; x[m * 4 + 3] = t.w;
      }
    }
    if (r == pg64) {
#pragma unroll
      for (int m4 = 0; m4 < 4; ++m4)
        *(float4*)&prow0[0][q * 16 + m4 * 4] =
            make_float4(x[m4 * 4], x[m4 * 4 + 1], x[m4 * 4 + 2], x[m4 * 4 + 3]);
    }
    if (r == pg64 + 1) {
#pragma unroll
      for (int m4 = 0; m4 < 4; ++m4)
        *(float4*)&prow1p[0][q * 16 + m4 * 4] =
            make_float4(x[m4 * 4], x[m4 * 4 + 1], x[m4 * 4 + 2], x[m4 * 4 + 3]);
    }
    if (q == 0) { fac0[0][r] = x[0]; fac1p[0][r] = x[1]; }
    __syncthreads();

#pragma unroll
    for (int t = 0; t < 32; ++t) {
      const int buf = t & 1, nb = buf ^ 1;
      const int j0 = 2 * t, j1 = 2 * t + 1;
      const int p0g = pg64 + j0, p1g = pg64 + j1;
      float piv0 = prow0[buf][j0];
      float ip0 = 1.0f / piv0;
      float c1 = fac0[buf][p1g] * ip0;
      float pr0j1 = prow0[buf][j1];
      float piv1 = fmaf(-c1, pr0j1, prow1p[buf][j1]);
      float ip1 = 1.0f / piv1;
      bool d0 = (r == p0g), d1 = (r == p1g);
      float g0 = fac0[buf][r] * ip0;
      float f1 = d0 ? ip0 * pr0j1 : fmaf(-g0, pr0j1, fac1p[buf][r]);
      float g1 = f1 * ip1;
#pragma unroll
      for (int m = 0; m < 16; ++m) {
        float p0v = prow0[buf][q * 16 + m];
        float p1v = fmaf(-c1, p0v, prow1p[buf][q * 16 + m]);
        float y = d0 ? p0v * ip0 : fmaf(-g0, p0v, x[m]);
        float z = d1 ? p1v * ip1 : fmaf(-g1, p1v, y);
        x[m] = z;
      }
      const int jo = j0 >> 4;
      if (q == jo) {
        float v0 = d0 ? ip0 : (0.f - g0);
        float p1_at_j0 = 0.f - c1;
        x[j0 & 15] = d1 ? p1_at_j0 * ip1 : fmaf(-g1, p1_at_j0, v0);
        x[j1 & 15] = d1 ? ip1 : (0.f - g1);
      }
      if (t < 31) {
        const int n0 = j0 + 2, n1 = j1 + 2;
        if (r == pg64 + n0) {
#pragma unroll
          for (int m4 = 0; m4 < 4; ++m4)
            *(float4*)&prow0[nb][q * 16 + m4 * 4] =
                make_float4(x[m4 * 4], x[m4 * 4 + 1], x[m4 * 4 + 2], x[m4 * 4 + 3]);
        }
        if (r == pg64 + n1) {
#pragma unroll
          for (int m4 = 0; m4 < 4; ++m4)
            *(float4*)&prow1p[nb][q * 16 + m4 * 4] =
                make_float4(x[m4 * 4], x[m4 * 4 + 1], x[m4 * 4 + 2], x[m4 * 4 + 3]);
        }
        const int jn = n0 >> 4;
        if (q == jn) { fac0[nb][r] = x[n0 & 15]; fac1p[nb][r] = x[n1 & 15]; }
      }
      __syncthreads();
    }

#pragma unroll
    for (int m = 0; m < 16; ++m) Mt[q * 16 + m][r] = x[m];
    __syncthreads();

    {
      int j = tid >> 4, rseg = (tid & 15) * 16;
      float* dst = Mtg + (((size_t)b * 4 + pg) * 64 + j) * 256 + rseg;
#pragma unroll
      for (int m = 0; m < 4; ++m) {
        float4 t = make_float4(Mt[j][rseg + m * 4 + 0], Mt[j][rseg + m * 4 + 1],
                               Mt[j][rseg + m * 4 + 2], Mt[j][rseg + m * 4 + 3]);
        *(float4*)(dst + m * 4) = t;
      }
    }

    int W = (3 - pg) * 64;
    if (W > 0) {
      int c_off = pg64 + 64;
      {
        int cpt = W >> 4;
        int jr = tid >> 4, tc = tid & 15;
        const float* src = A + (size_t)(pg64 + jr) * 256 + c_off + tc * cpt;
        for (int m = 0; m < cpt; m += 4) {
          float4 t = *(const float4*)(src + m);
          *(float4*)&Sst[jr][tc * cpt + m] = t;
        }
      }
      __syncthreads();
      int colTiles = W >> 3;
      int rt = tid / colTiles;
      int ctile = tid - rt * colTiles;
      if (rt < 32) {
        int r0 = rt * 8, c0 = ctile * 8;
        float acc[8][8];
#pragma unroll
        for (int i = 0; i < 8; ++i)
#pragma unroll
          for (int j2 = 0; j2 < 8; ++j2) acc[i][j2] = 0.f;
        for (int j = 0; j < 64; ++j) {
          float4 m0 = *(const float4*)&Mt[j][r0];
          float4 m1 = *(const float4*)&Mt[j][r0 + 4];
          float4 s0 = *(const float4*)&Sst[j][c0];
          float4 s1 = *(const float4*)&Sst[j][c0 + 4];
          float mv[8] = {m0.x, m0.y, m0.z, m0.w, m1.x, m1.y, m1.z, m1.w};
          float sv[8] = {s0.x, s0.y, s0.z, s0.w, s1.x, s1.y, s1.z, s1.w};
#pragma unroll
          for (int i = 0; i < 8; ++i)
#pragma unroll
            for (int j2 = 0; j2 < 8; ++j2)
              acc[i][j2] = fmaf(mv[i], sv[j2], acc[i][j2]);
        }
#pragma unroll
        for (int ii = 0; ii < 8; ++ii) {
          int row = r0 + ii;
          bool inPanel = ((row >> 6) == pg);
          float* dst = A + (size_t)row * 256 + c_off + c0;
          float4 o0 = make_float4(acc[ii][0], acc[ii][1], acc[ii][2], acc[ii][3]);
          float4 o1 = make_float4(acc[ii][4], acc[ii][5], acc[ii][6], acc[ii][7]);
          if (!inPanel) {
            float4 a0 = *(const float4*)(dst);
            float4 a1 = *(const float4*)(dst + 4);
            o0.x += a0.x; o0.y += a0.y; o0.z += a0.z; o0.w += a0.w;
            o1.x += a1.x; o1.y += a1.y; o1.z += a1.z; o1.w += a1.w;
          }
          *(float4*)(dst) = o0;
          *(float4*)(dst + 4) = o1;
        }
      }
      __syncthreads();
    }
  }
}

// ---------------- gj_apply: B <- E4 E3 E2 E1 B, 8 col-stripes x 32 batches --
__global__ __launch_bounds__(256) void gj_apply(float* __restrict__ Sb,
                                                const float* __restrict__ Mtg) {
  int blk = blockIdx.x;             // 256
  int b = blk >> 3;
  int cbase = (blk & 7) * 32;
  float* Bm = Sb + ((size_t)b * 2 + 1) * 65536;
  int tid = threadIdx.x;
  int rt = tid >> 3;
  int ct = tid & 7;

  __shared__ __align__(16) float Mt[64][260];
  __shared__ __align__(8) float Bp[64][34];

  float4 breg[8];
#pragma unroll
  for (int i = 0; i < 8; ++i)
    breg[i] = *(const float4*)(Bm + (size_t)(rt * 8 + i) * 256 + cbase + ct * 4);

  for (int pg = 0; pg < 4; ++pg) {
    __syncthreads();
    {
      int j = tid >> 2, seg = (tid & 3) * 64;
      const float* src = Mtg + (((size_t)b * 4 + pg) * 64 + j) * 256 + seg;
#pragma unroll
      for (int m = 0; m < 16; ++m) {
        float4 t = *(const float4*)(src + m * 4);
        *(float4*)&Mt[j][seg + m * 4] = t;
      }
    }
    if (rt >= pg * 8 && rt < (pg + 1) * 8) {
#pragma unroll
      for (int i = 0; i < 8; ++i) {
        int j = (rt - pg * 8) * 8 + i;
        *(float2*)&Bp[j][ct * 4]     = make_float2(breg[i].x, breg[i].y);
        *(float2*)&Bp[j][ct * 4 + 2] = make_float2(breg[i].z, breg[i].w);
      }
    }
    __syncthreads();

    float acc[8][4];
#pragma unroll
    for (int i = 0; i < 8; ++i)
#pragma unroll
      for (int c = 0; c < 4; ++c) acc[i][c] = 0.f;
#pragma unroll 4
    for (int j = 0; j < 64; ++j) {
      float4 m0 = *(const float4*)&Mt[j][rt * 8];
      float4 m1 = *(const float4*)&Mt[j][rt * 8 + 4];
      float2 b0 = *(const float2*)&Bp[j][ct * 4];
      float2 b1 = *(const float2*)&Bp[j][ct * 4 + 2];
      float mv[8] = {m0.x, m0.y, m0.z, m0.w, m1.x, m1.y, m1.z, m1.w};
      float bv4[4] = {b0.x, b0.y, b1.x, b1.y};
#pragma unroll
      for (int i = 0; i < 8; ++i)
#pragma unroll
        for (int c = 0; c < 4; ++c)
          acc[i][c] = fmaf(mv[i], bv4[c], acc[i][c]);
    }
    bool inPanel = ((rt >> 3) == pg);
#pragma unroll
    for (int i = 0; i < 8; ++i) {
      if (inPanel) {
        breg[i] = make_float4(acc[i][0], acc[i][1], acc[i][2], acc[i][3]);
      } else {
        breg[i].x += acc[i][0]; breg[i].y += acc[i][1];
        breg[i].z += acc[i][2]; breg[i].w += acc[i][3];
      }
    }
  }

#pragma unroll
  for (int i = 0; i < 8; ++i)
    *(float4*)(Bm + (size_t)(rt * 8 + i) * 256 + cbase + ct * 4) = breg[i];
}

// ------- softmax_h: row stats then h[b,e] = sum_d qsum[d]*softmax(X[d,:])[e]
__global__ void softmax_h(const float* __restrict__ S,
                          const float* __restrict__ uvec,
                          float* __restrict__ out) {
  int b = blockIdx.x;
  const float* X = S + ((size_t)b * 2 + 1) * 65536;
  int tid = threadIdx.x; int lane = tid & 63; int wv = tid >> 6;
  __shared__ float mrow[256], qos[256];
  __shared__ float qs_s[256];
  qs_s[tid] = uvec[((size_t)2 * 32 + b) * DDIM + tid];
  for (int rr = 0; rr < 64; ++rr) {
    int row = rr * 4 + wv;
    float x0 = X[row * 256 + lane];
    float x1 = X[row * 256 + lane + 64];
    float x2 = X[row * 256 + lane + 128];
    float x3 = X[row * 256 + lane + 192];
    float m = fmaxf(fmaxf(x0, x1), fmaxf(x2, x3));
    for (int o = 32; o > 0; o >>= 1) m = fmaxf(m, __shfl_xor(m, o, 64));
    float s = expf(x0 - m) + expf(x1 - m) + expf(x2 - m) + expf(x3 - m);
    for (int o = 32; o > 0; o >>= 1) s += __shfl_xor(s, o, 64);
    if (lane == 0) {
      mrow[row] = m;
      qos[row] = s;
    }
  }
  __syncthreads();
  qos[tid] = qs_s[tid] / qos[tid];
  __syncthreads();
  int e = tid;
  float acc = 0.f;
  for (int d = 0; d < 256; ++d)
    acc += qos[d] * expf(X[d * 256 + e] - mrow[d]);
  out[(size_t)b * 256 + e] = acc;
}

extern "C" void kernel_launch(void* const* d_in, const int* in_sizes, int n_in,
                              void* d_out, int out_size, void* d_ws, size_t ws_size,
                              hipStream_t stream) {
  const float* q  = (const float*)d_in[0];
  const float* k  = (const float*)d_in[1];
  const float* v  = (const float*)d_in[2];
  const float* Wq = (const float*)d_in[3];
  const float* bq = (const float*)d_in[4];
  const float* Wk = (const float*)d_in[5];
  const float* bk = (const float*)d_in[6];
  const float* Wv = (const float*)d_in[7];
  const float* bv = (const float*)d_in[8];
  float* out = (float*)d_out;

  float* ws   = (float*)d_ws;
  float* Gbuf = ws;                                    // Gram partial 0; later Mtg
  float* Tbuf = Gbuf + (size_t)32 * 2 * 65536;         // [32][2][256][256]
  float* Sbuf = Tbuf + (size_t)32 * 2 * 65536;         // Gram partial 1 -> (A, B->X)
  float* part = Sbuf + (size_t)32 * 2 * 65536;         // [16][32][256] (q partials)
  float* svec = part + (size_t)16 * 3 * 32 * 256;      // [2][3][32][256]
  float* uvec = svec + (size_t)2 * 3 * 32 * 256;       // [3][32][256]

  gram_fused<<<1536, 256, 0, stream>>>(k, v, q, Gbuf, Sbuf, svec, part);
  smallvec<<<32, 256, 0, stream>>>(Wq, bq, Wk, Wv, part, svec, uvec);
  gemm_pass1<<<dim3(16, 2, 32), 256, 0, stream>>>(Wk, Gbuf, Sbuf, Tbuf);
  gemm_pass2<<<dim3(16, 2, 32), 256, 0, stream>>>(Tbuf, Wk, Wv, Sbuf, uvec, bk, bv);
  gj_factor<<<32, 1024, 0, stream>>>(Sbuf, Gbuf);
  gj_apply<<<256, 256, 0, stream>>>(Sbuf, Gbuf);
  softmax_h<<<32, 256, 0, stream>>>(Sbuf, uvec, out);
}

// Round 16
// 482.874 us; speedup vs baseline: 1.0075x; 1.0075x over previous
//
#include <hip/hip_runtime.h>
#include <math.h>

#define FDIM 4096
#define DDIM 256
#define ALPHA_R 0.001f
#define SVH (3 * 32 * 256)

typedef __attribute__((ext_vector_type(8))) short short8;
typedef __attribute__((ext_vector_type(4))) float f32x4;

__device__ __forceinline__ unsigned cvt_pk_bf16(float lo_e, float hi_e) {
  unsigned r;
  asm("v_cvt_pk_bf16_f32 %0, %1, %2" : "=v"(r) : "v"(lo_e), "v"(hi_e));
  return r;
}

// split 8 fp32 -> hi/lo packed uint4s
__device__ __forceinline__ void hilo8(const float* x, uint4& H, uint4& L) {
  unsigned h0 = cvt_pk_bf16(x[0], x[1]);
  unsigned h1 = cvt_pk_bf16(x[2], x[3]);
  unsigned h2 = cvt_pk_bf16(x[4], x[5]);
  unsigned h3 = cvt_pk_bf16(x[6], x[7]);
  unsigned l0 = cvt_pk_bf16(x[0] - __uint_as_float(h0 << 16),
                            x[1] - __uint_as_float(h0 & 0xFFFF0000u));
  unsigned l1 = cvt_pk_bf16(x[2] - __uint_as_float(h1 << 16),
                            x[3] - __uint_as_float(h1 & 0xFFFF0000u));
  unsigned l2 = cvt_pk_bf16(x[4] - __uint_as_float(h2 << 16),
                            x[5] - __uint_as_float(h2 & 0xFFFF0000u));
  unsigned l3 = cvt_pk_bf16(x[6] - __uint_as_float(h3 << 16),
                            x[7] - __uint_as_float(h3 & 0xFFFF0000u));
  H = make_uint4(h0, h1, h2, h3);
  L = make_uint4(l0, l1, l2, l3);
}

// ---- fused: split-F MFMA Gram (blocks 0..1023) + q column-sum (1024..1535) --
__global__ __launch_bounds__(256) void gram_fused(const float* __restrict__ kg,
                                                  const float* __restrict__ vg,
                                                  const float* __restrict__ qg,
                                                  float* __restrict__ Gp0,
                                                  float* __restrict__ Gp1,
                                                  float* __restrict__ svec,
                                                  float* __restrict__ part) {
  __shared__ __align__(16) char smem[31808];
  int flat = blockIdx.x;            // 1536
  int tid = threadIdx.x;

  if (flat >= 1024) {
    float (*redq)[64][4] = (float (*)[64][4])smem;
    int cs = flat - 1024;           // 512 = 16 chunks x 32 batches
    int chunk = cs & 15, b = cs >> 4;
    int rg = tid >> 6, dq = tid & 63;
    const float* p = qg + ((size_t)b * FDIM + chunk * 256 + rg) * DDIM + dq * 4;
    float4 s = make_float4(0.f, 0.f, 0.f, 0.f);
    for (int i = 0; i < 64; ++i) {
      float4 t = *(const float4*)(p + (size_t)i * 4 * DDIM);
      s.x += t.x; s.y += t.y; s.z += t.z; s.w += t.w;
    }
    *(float4*)&redq[rg][dq][0] = s;
    __syncthreads();
    if (rg == 0) {
      float4 a0 = *(float4*)&redq[0][dq][0];
      float4 a1 = *(float4*)&redq[1][dq][0];
      float4 a2 = *(float4*)&redq[2][dq][0];
      float4 a3 = *(float4*)&redq[3][dq][0];
      float4 t = make_float4(a0.x + a1.x + a2.x + a3.x, a0.y + a1.y + a2.y + a3.y,
                             a0.z + a1.z + a2.z + a3.z, a0.w + a1.w + a2.w + a3.w);
      *(float4*)(part + ((size_t)chunk * 32 + b) * DDIM + dq * 4) = t;
    }
    return;
  }

  // gram path (1024 blocks = 8 xcd x 4 b x 16 tile x 2 half)
  unsigned short (*Ah)[40] = (unsigned short (*)[40])(smem);
  unsigned short (*Al)[40] = (unsigned short (*)[40])(smem + 5120);
  unsigned short (*Bh)[40] = (unsigned short (*)[40])(smem + 10240);
  unsigned short (*Bl)[40] = (unsigned short (*)[40])(smem + 15360);
  unsigned short (*Ch)[40] = (unsigned short (*)[40])(smem + 20480);
  unsigned short (*Cl)[40] = (unsigned short (*)[40])(smem + 25600);
  float (*sred)[68] = (float (*)[68])(smem + 30720);

  int xcd = flat & 7, s = flat >> 3;
  int b = xcd * 4 + (s >> 5);
  int rem = s & 31;
  int tile = rem >> 1;
  int half = rem & 1;
  int tm = tile >> 2, tn = tile & 3;
  int mBase = tm * 64, nBase = tn * 64;
  const float* Kb = kg + (size_t)b * FDIM * DDIM;
  const float* Vb = vg + (size_t)b * FDIM * DDIM;

  int w = tid >> 6, lane = tid & 63;
  int wr = w >> 1, wc = w & 1;
  int lrow = lane & 15;
  int kof = (lane >> 4) * 8;

  const float* pA = Kb + mBase + lane;
  const float* pB = Kb + nBase + lane;
  const float* pC = Vb + nBase + lane;

  bool doK = (tn == 0), doV = (tm == 0);
  float sK = 0.f, sV = 0.f;
  int fBase = half * 2048;

  float xa[8], xb[8], xc[8];
  auto loadIter = [&](int it) {
    int f = fBase + it * 32 + w * 8;
#pragma unroll
    for (int j = 0; j < 8; ++j) {
      xa[j] = pA[(size_t)(f + j) * DDIM];
      xb[j] = pB[(size_t)(f + j) * DDIM];
      xc[j] = pC[(size_t)(f + j) * DDIM];
    }
  };
  auto stash = [&](const float* x, unsigned short (*H)[40], unsigned short (*L)[40]) {
    uint4 hh, ll;
    hilo8(x, hh, ll);
    *(uint4*)&H[lane][w * 8] = hh;
    *(uint4*)&L[lane][w * 8] = ll;
  };

  f32x4 acc0[2][2], acc1[2][2];
#pragma unroll
  for (int mt = 0; mt < 2; ++mt)
#pragma unroll
    for (int nt = 0; nt < 2; ++nt) {
      acc0[mt][nt] = (f32x4){0.f, 0.f, 0.f, 0.f};
      acc1[mt][nt] = (f32x4){0.f, 0.f, 0.f, 0.f};
    }

  loadIter(0);
  for (int it = 0; it < 64; ++it) {
    __syncthreads();
    stash(xa, Ah, Al);
    stash(xb, Bh, Bl);
    stash(xc, Ch, Cl);
    if (doK) sK += ((xa[0] + xa[1]) + (xa[2] + xa[3])) + ((xa[4] + xa[5]) + (xa[6] + xa[7]));
    if (doV) sV += ((xc[0] + xc[1]) + (xc[2] + xc[3])) + ((xc[4] + xc[5]) + (xc[6] + xc[7]));
    __syncthreads();
    if (it < 63) loadIter(it + 1);

    short8 bh[2], bl[2], ch[2], cl[2];
#pragma unroll
    for (int nt = 0; nt < 2; ++nt) {
      int rB = wc * 32 + nt * 16 + lrow;
      bh[nt] = *(const short8*)&Bh[rB][kof];
      bl[nt] = *(const short8*)&Bl[rB][kof];
      ch[nt] = *(const short8*)&Ch[rB][kof];
      cl[nt] = *(const short8*)&Cl[rB][kof];
    }
    __builtin_amdgcn_s_setprio(1);
#pragma unroll
    for (int mt = 0; mt < 2; ++mt) {
      int rA = wr * 32 + mt * 16 + lrow;
      short8 ah = *(const short8*)&Ah[rA][kof];
      short8 al = *(const short8*)&Al[rA][kof];
#pragma unroll
      for (int nt = 0; nt < 2; ++nt) {
        f32x4 t = acc0[mt][nt];
        t = __builtin_amdgcn_mfma_f32_16x16x32_bf16(ah, bh[nt], t, 0, 0, 0);
        t = __builtin_amdgcn_mfma_f32_16x16x32_bf16(ah, bl[nt], t, 0, 0, 0);
        t = __builtin_amdgcn_mfma_f32_16x16x32_bf16(al, bh[nt], t, 0, 0, 0);
        acc0[mt][nt] = t;
        f32x4 u = acc1[mt][nt];
        u = __builtin_amdgcn_mfma_f32_16x16x32_bf16(ah, ch[nt], u, 0, 0, 0);
        u = __builtin_amdgcn_mfma_f32_16x16x32_bf16(ah, cl[nt], u, 0, 0, 0);
        u = __builtin_amdgcn_mfma_f32_16x16x32_bf16(al, ch[nt], u, 0, 0, 0);
        acc1[mt][nt] = u;
      }
    }
    __builtin_amdgcn_s_setprio(0);
  }

  float* Gp = half ? Gp1 : Gp0;
  float* G0 = Gp + ((size_t)b * 2) * 65536;
  float* G1 = G0 + 65536;
#pragma unroll
  for (int mt = 0; mt < 2; ++mt)
#pragma unroll
    for (int nt = 0; nt < 2; ++nt)
#pragma unroll
      for (int r = 0; r < 4; ++r) {
        int row = mBase + wr * 32 + mt * 16 + (lane >> 4) * 4 + r;
        int col = nBase + wc * 32 + nt * 16 + (lane & 15);
        G0[(size_t)row * DDIM + col] = acc0[mt][nt][r];
        G1[(size_t)row * DDIM + col] = acc1[mt][nt][r];
      }

  float* svecH = svec + (size_t)half * SVH;
  if (doK) {
    __syncthreads();
    sred[w][lane] = sK;
    __syncthreads();
    if (tid < 64) {
      float t = sred[0][tid] + sred[1][tid] + sred[2][tid] + sred[3][tid];
      svecH[(size_t)1 * 32 * 256 + (size_t)b * 256 + mBase + tid] = t;
    }
  }
  if (doV) {
    __syncthreads();
    sred[w][lane] = sV;
    __syncthreads();
    if (tid < 64) {
      float t = sred[0][tid] + sred[1][tid] + sred[2][tid] + sred[3][tid];
      svecH[(size_t)2 * 32 * 256 + (size_t)b * 256 + nBase + tid] = t;
    }
  }
}

// ------- small vectors: sums q-partials + both svec halves ------------------
__global__ void smallvec(const float* __restrict__ Wq, const float* __restrict__ bq,
                         const float* __restrict__ Wk, const float* __restrict__ Wv,
                         const float* __restrict__ part,
                         const float* __restrict__ svec, float* __restrict__ uvec) {
  int b = blockIdx.x; int d = threadIdx.x;
  __shared__ float sq[256], sk[256], sv[256];
  float sqv = 0.f;
  for (int c = 0; c < 16; ++c) sqv += part[((size_t)c * 32 + b) * DDIM + d];
  sq[d] = sqv;
  sk[d] = svec[((size_t)1 * 32 + b) * DDIM + d] + svec[SVH + ((size_t)1 * 32 + b) * DDIM + d];
  sv[d] = svec[((size_t)2 * 32 + b) * DDIM + d] + svec[SVH + ((size_t)2 * 32 + b) * DDIM + d];
  __syncthreads();
  float uk = 0.f, uv = 0.f, uq = 0.f;
  for (int j = 0; j < 256; j += 4) {
    float4 wk4 = *(const float4*)(Wk + (size_t)d * DDIM + j);
    float4 wv4 = *(const float4*)(Wv + (size_t)d * DDIM + j);
    float4 wq4 = *(const float4*)(Wq + (size_t)d * DDIM + j);
    uk += wk4.x * sk[j] + wk4.y * sk[j + 1] + wk4.z * sk[j + 2] + wk4.w * sk[j + 3];
    uv += wv4.x * sv[j] + wv4.y * sv[j + 1] + wv4.z * sv[j + 2] + wv4.w * sv[j + 3];
    uq += wq4.x * sq[j] + wq4.y * sq[j + 1] + wq4.z * sq[j + 2] + wq4.w * sq[j + 3];
  }
  uvec[((size_t)0 * 32 + b) * DDIM + d] = uk;
  uvec[((size_t)1 * 32 + b) * DDIM + d] = uv;
  uvec[((size_t)2 * 32 + b) * DDIM + d] = uq + 4096.f * bq[d];
}

// ------- T[b][w] = Wk @ (Gp0+Gp1)[b][w]  (nn GEMM, MFMA bf16 hi/lo 4-term) --
__global__ __launch_bounds__(256) void gemm_pass1(const float* __restrict__ Wk,
                                                  const float* __restrict__ Gp0,
                                                  const float* __restrict__ Gp1,
                                                  float* __restrict__ T) {
  int tile = blockIdx.x, wsel = blockIdx.y, b = blockIdx.z;
  int tm = tile >> 2, tn = tile & 3;
  int mBase = tm * 64, nBase = tn * 64;
  const float* A = Wk;
  const float* B0 = Gp0 + ((size_t)b * 2 + wsel) * 65536;
  const float* B1 = Gp1 + ((size_t)b * 2 + wsel) * 65536;
  float* C = T + ((size_t)b * 2 + wsel) * 65536;

  __shared__ __align__(16) unsigned short Ah[64][40], Al[64][40];
  __shared__ __align__(16) unsigned short Bh[64][40], Bl[64][40];

  int tid = threadIdx.x;
  int w = tid >> 6, lane = tid & 63;
  int wr = w >> 1, wc = w & 1;
  int lrow = lane & 15;
  int kof = (lane >> 4) * 8;
  int ar = tid >> 2, aq = tid & 3;
  const float* pArow = A + (size_t)(mBase + ar) * DDIM + aq * 8;
  int bw = tid >> 6;
  const float* pB0 = B0 + nBase + lane;
  const float* pB1 = B1 + nBase + lane;

  float xa[8], xb[8];
  auto loadIter = [&](int k0) {
    float4 a0 = *(const float4*)(pArow + k0);
    float4 a1 = *(const float4*)(pArow + k0 + 4);
    xa[0] = a0.x; xa[1] = a0.y; xa[2] = a0.z; xa[3] = a0.w;
    xa[4] = a1.x; xa[5] = a1.y; xa[6] = a1.z; xa[7] = a1.w;
#pragma unroll
    for (int j = 0; j < 8; ++j) {
      size_t o = (size_t)(k0 + bw * 8 + j) * DDIM;
      xb[j] = pB0[o] + pB1[o];
    }
  };

  f32x4 acc[2][2];
#pragma unroll
  for (int mt = 0; mt < 2; ++mt)
#pragma unroll
    for (int nt = 0; nt < 2; ++nt) acc[mt][nt] = (f32x4){0.f, 0.f, 0.f, 0.f};

  loadIter(0);
  for (int it = 0; it < 8; ++it) {
    __syncthreads();
    {
      uint4 hh, ll;
      hilo8(xa, hh, ll);
      *(uint4*)&Ah[ar][aq * 8] = hh;
      *(uint4*)&Al[ar][aq * 8] = ll;
      hilo8(xb, hh, ll);
      *(uint4*)&Bh[lane][bw * 8] = hh;
      *(uint4*)&Bl[lane][bw * 8] = ll;
    }
    __syncthreads();
    if (it < 7) loadIter((it + 1) * 32);

    short8 bh[2], bl[2];
#pragma unroll
    for (int nt = 0; nt < 2; ++nt) {
      int rB = wc * 32 + nt * 16 + lrow;
      bh[nt] = *(const short8*)&Bh[rB][kof];
      bl[nt] = *(const short8*)&Bl[rB][kof];
    }
    __builtin_amdgcn_s_setprio(1);
#pragma unroll
    for (int mt = 0; mt < 2; ++mt) {
      int rA = wr * 32 + mt * 16 + lrow;
      short8 ah = *(const short8*)&Ah[rA][kof];
      short8 al = *(const short8*)&Al[rA][kof];
#pragma unroll
      for (int nt = 0; nt < 2; ++nt) {
        f32x4 t = acc[mt][nt];
        t = __builtin_amdgcn_mfma_f32_16x16x32_bf16(ah, bh[nt], t, 0, 0, 0);
        t = __builtin_amdgcn_mfma_f32_16x16x32_bf16(ah, bl[nt], t, 0, 0, 0);
        t = __builtin_amdgcn_mfma_f32_16x16x32_bf16(al, bh[nt], t, 0, 0, 0);
        t = __builtin_amdgcn_mfma_f32_16x16x32_bf16(al, bl[nt], t, 0, 0, 0);
        acc[mt][nt] = t;
      }
    }
    __builtin_amdgcn_s_setprio(0);
  }

#pragma unroll
  for (int mt = 0; mt < 2; ++mt)
#pragma unroll
    for (int nt = 0; nt < 2; ++nt)
#pragma unroll
      for (int r = 0; r < 4; ++r) {
        int row = mBase + wr * 32 + mt * 16 + (lane >> 4) * 4 + r;
        int col = nBase + wc * 32 + nt * 16 + (lane & 15);
        C[(size_t)row * DDIM + col] = acc[mt][nt][r];
      }
}

// -- S[b][w] = T[b][w] @ W^T + rank1 + alpha*I (nt GEMM, MFMA 4-term) --------
__global__ __launch_bounds__(256) void gemm_pass2(const float* __restrict__ T,
                                                  const float* __restrict__ Wk,
                                                  const float* __restrict__ Wv,
                                                  float* __restrict__ S,
                                                  const float* __restrict__ uvec,
                                                  const float* __restrict__ bk,
                                                  const float* __restrict__ bv) {
  int tile = blockIdx.x, wsel = blockIdx.y, b = blockIdx.z;
  int tm = tile >> 2, tn = tile & 3;
  int mBase = tm * 64, nBase = tn * 64;
  const float* A = T + ((size_t)b * 2 + wsel) * 65536;
  const float* W = wsel ? Wv : Wk;
  float* C = S + ((size_t)b * 2 + wsel) * 65536;

  __shared__ __align__(16) unsigned short Ah[64][40], Al[64][40];
  __shared__ __align__(16) unsigned short Bh[64][40], Bl[64][40];

  int tid = threadIdx.x;
  int w = tid >> 6, lane = tid & 63;
  int wr = w >> 1, wc = w & 1;
  int lrow = lane & 15;
  int kof = (lane >> 4) * 8;
  int ar = tid >> 2, aq = tid & 3;
  const float* pArow = A + (size_t)(mBase + ar) * DDIM + aq * 8;
  const float* pBrow = W + (size_t)(nBase + ar) * DDIM + aq * 8;

  float xa[8], xb[8];
  auto loadIter = [&](int k0) {
    float4 a0 = *(const float4*)(pArow + k0);
    float4 a1 = *(const float4*)(pArow + k0 + 4);
    xa[0] = a0.x; xa[1] = a0.y; xa[2] = a0.z; xa[3] = a0.w;
    xa[4] = a1.x; xa[5] = a1.y; xa[6] = a1.z; xa[7] = a1.w;
    float4 b0 = *(const float4*)(pBrow + k0);
    float4 b1 = *(const float4*)(pBrow + k0 + 4);
    xb[0] = b0.x; xb[1] = b0.y; xb[2] = b0.z; xb[3] = b0.w;
    xb[4] = b1.x; xb[5] = b1.y; xb[6] = b1.z; xb[7] = b1.w;
  };

  f32x4 acc[2][2];
#pragma unroll
  for (int mt = 0; mt < 2; ++mt)
#pragma unroll
    for (int nt = 0; nt < 2; ++nt) acc[mt][nt] = (f32x4){0.f, 0.f, 0.f, 0.f};

  loadIter(0);
  for (int it = 0; it < 8; ++it) {
    __syncthreads();
    {
      uint4 hh, ll;
      hilo8(xa, hh, ll);
      *(uint4*)&Ah[ar][aq * 8] = hh;
      *(uint4*)&Al[ar][aq * 8] = ll;
      hilo8(xb, hh, ll);
      *(uint4*)&Bh[ar][aq * 8] = hh;
      *(uint4*)&Bl[ar][aq * 8] = ll;
    }
    __syncthreads();
    if (it < 7) loadIter((it + 1) * 32);

    short8 bh[2], bl[2];
#pragma unroll
    for (int nt = 0; nt < 2; ++nt) {
      int rB = wc * 32 + nt * 16 + lrow;
      bh[nt] = *(const short8*)&Bh[rB][kof];
      bl[nt] = *(const short8*)&Bl[rB][kof];
    }
    __builtin_amdgcn_s_setprio(1);
#pragma unroll
    for (int mt = 0; mt < 2; ++mt) {
      int rA = wr * 32 + mt * 16 + lrow;
      short8 ah = *(const short8*)&Ah[rA][kof];
      short8 al = *(const short8*)&Al[rA][kof];
#pragma unroll
      for (int nt = 0; nt < 2; ++nt) {
        f32x4 t = acc[mt][nt];
        t = __builtin_amdgcn_mfma_f32_16x16x32_bf16(ah, bh[nt], t, 0, 0, 0);
        t = __builtin_amdgcn_mfma_f32_16x16x32_bf16(ah, bl[nt], t, 0, 0, 0);
        t = __builtin_amdgcn_mfma_f32_16x16x32_bf16(al, bh[nt], t, 0, 0, 0);
        t = __builtin_amdgcn_mfma_f32_16x16x32_bf16(al, bl[nt], t, 0, 0, 0);
        acc[mt][nt] = t;
      }
    }
    __builtin_amdgcn_s_setprio(0);
  }

  // fused rank-1 epilogue
  const float* uk = uvec + ((size_t)0 * 32 + b) * DDIM;
  const float* uvv = uvec + ((size_t)1 * 32 + b) * DDIM;
#pragma unroll
  for (int mt = 0; mt < 2; ++mt)
#pragma unroll
    for (int nt = 0; nt < 2; ++nt) {
      int col = nBase + wc * 32 + nt * 16 + (lane & 15);
      float ue = wsel ? uvv[col] : uk[col];
      float be = wsel ? bv[col] : bk[col];
#pragma unroll
      for (int r = 0; r < 4; ++r) {
        int row = mBase + wr * 32 + mt * 16 + (lane >> 4) * 4 + r;
        float add = uk[row] * be + bk[row] * ue + 4096.f * bk[row] * be;
        if (wsel == 0 && row == col) add += ALPHA_R;
        C[(size_t)row * DDIM + col] = acc[mt][nt][r] + add;
      }
    }
}

// -- gj_factor: R6 single-pivot structure + VECTORIZED prow reads (4x b128
// instead of 16x b32 per thread per pivot) -> cuts LDS issue ~3x in the
// issue-bound pivot loop. Math identical to R6.
__global__ __launch_bounds__(1024, 4) void gj_factor(float* __restrict__ Sb,
                                                     float* __restrict__ Mtg) {
  int b = blockIdx.x;
  float* A = Sb + (size_t)b * 2 * 65536;
  int tid = threadIdx.x;
  int r = tid >> 2;
  int q = tid & 3;

  __shared__ __align__(16) float Mt[64][264];
  __shared__ __align__(16) float Sst[64][200];
  __shared__ __align__(16) float prow[2][64];
  __shared__ float fac[2][256];

  for (int pg = 0; pg < 4; ++pg) {
    float x[16];
    {
      const float* Ar = A + (size_t)r * 256 + pg * 64 + q * 16;
#pragma unroll
      for (int m = 0; m < 4; ++m) {
        float4 t = *(const float4*)(Ar + m * 4);
        x[m * 4 + 0] = t.x; x[m * 4 + 1] = t.y;
        x[m * 4 + 2] = t.z; x[m * 4 + 3] = t.w;
      }
    }
    if (r == pg * 64) {
      *(float4*)&prow[0][q * 16 + 0]  = make_float4(x[0], x[1], x[2], x[3]);
      *(float4*)&prow[0][q * 16 + 4]  = make_float4(x[4], x[5], x[6], x[7]);
      *(float4*)&prow[0][q * 16 + 8]  = make_float4(x[8], x[9], x[10], x[11]);
      *(float4*)&prow[0][q * 16 + 12] = make_float4(x[12], x[13], x[14], x[15]);
    }
    if (q == 0) fac[0][r] = x[0];
    __syncthreads();

#pragma unroll
    for (int jo = 0; jo < 4; ++jo) {
#pragma unroll
      for (int ji = 0; ji < 16; ++ji) {
        const int j = jo * 16 + ji;
        const int p = pg * 64 + j;
        const int buf = j & 1, nb = buf ^ 1;
        float piv = fac[buf][p];
        float ip = 1.0f / piv;
        float g = fac[buf][r] * ip;
        bool diag = (r == p);
        // vectorized pivot-row reads: 4x b128
        float4 p0 = *(const float4*)&prow[buf][q * 16 + 0];
        float4 p1 = *(const float4*)&prow[buf][q * 16 + 4];
        float4 p2 = *(const float4*)&prow[buf][q * 16 + 8];
        float4 p3 = *(const float4*)&prow[buf][q * 16 + 12];
        float pv[16] = {p0.x, p0.y, p0.z, p0.w, p1.x, p1.y, p1.z, p1.w,
                        p2.x, p2.y, p2.z, p2.w, p3.x, p3.y, p3.z, p3.w};
#pragma unroll
        for (int m = 0; m < 16; ++m)
          x[m] = diag ? pv[m] * ip : fmaf(-g, pv[m], x[m]);
        if (q == jo) x[ji] = diag ? ip : (0.f - g);
        if (j < 63) {
          const int jn = j + 1;
          if (r == pg * 64 + jn) {
            *(float4*)&prow[nb][q * 16 + 0]  = make_float4(x[0], x[1], x[2], x[3]);
            *(float4*)&prow[nb][q * 16 + 4]  = make_float4(x[4], x[5], x[6], x[7]);
            *(float4*)&prow[nb][q * 16 + 8]  = make_float4(x[8], x[9], x[10], x[11]);
            *(float4*)&prow[nb][q * 16 + 12] = make_float4(x[12], x[13], x[14], x[15]);
          }
          if (q == (jn >> 4)) fac[nb][r] = x[jn & 15];
        }
        __syncthreads();
      }
    }
#pragma unroll
    for (int m = 0; m < 16; ++m) Mt[q * 16 + m][r] = x[m];
    __syncthreads();

    {
      int j = tid >> 4, rseg = (tid & 15) * 16;
      float* dst = Mtg + (((size_t)b * 4 + pg) * 64 + j) * 256 + rseg;
#pragma unroll
      for (int m = 0; m < 4; ++m) {
        float4 t = make_float4(Mt[j][rseg + m * 4 + 0], Mt[j][rseg + m * 4 + 1],
                               Mt[j][rseg + m * 4 + 2], Mt[j][rseg + m * 4 + 3]);
        *(float4*)(dst + m * 4) = t;
      }
    }

    int W = (3 - pg) * 64;
    if (W > 0) {
      int c_off = (pg + 1) * 64;
      {
        int cpt = W >> 4;
        int jr = tid >> 4, tc = tid & 15;
        const float* src = A + (size_t)(pg * 64 + jr) * 256 + c_off + tc * cpt;
        for (int m = 0; m < cpt; m += 4) {
          float4 t = *(const float4*)(src + m);
          *(float4*)&Sst[jr][tc * cpt + m] = t;
        }
      }
      __syncthreads();
      int colTiles = W >> 3;
      int rt = tid / colTiles;
      int ctile = tid - rt * colTiles;
      if (rt < 32) {
        int r0 = rt * 8, c0 = ctile * 8;
        float acc[8][8];
#pragma unroll
        for (int i = 0; i < 8; ++i)
#pragma unroll
          for (int j2 = 0; j2 < 8; ++j2) acc[i][j2] = 0.f;
        for (int j = 0; j < 64; ++j) {
          float4 m0 = *(const float4*)&Mt[j][r0];
          float4 m1 = *(const float4*)&Mt[j][r0 + 4];
          float4 s0 = *(const float4*)&Sst[j][c0];
          float4 s1 = *(const float4*)&Sst[j][c0 + 4];
          float mv[8] = {m0.x, m0.y, m0.z, m0.w, m1.x, m1.y, m1.z, m1.w};
          float sv[8] = {s0.x, s0.y, s0.z, s0.w, s1.x, s1.y, s1.z, s1.w};
#pragma unroll
          for (int i = 0; i < 8; ++i)
#pragma unroll
            for (int j2 = 0; j2 < 8; ++j2)
              acc[i][j2] = fmaf(mv[i], sv[j2], acc[i][j2]);
        }
#pragma unroll
        for (int ii = 0; ii < 8; ++ii) {
          int row = r0 + ii;
          bool inPanel = ((row >> 6) == pg);
          float* dst = A + (size_t)row * 256 + c_off + c0;
          float4 o0 = make_float4(acc[ii][0], acc[ii][1], acc[ii][2], acc[ii][3]);
          float4 o1 = make_float4(acc[ii][4], acc[ii][5], acc[ii][6], acc[ii][7]);
          if (!inPanel) {
            float4 a0 = *(const float4*)(dst);
            float4 a1 = *(const float4*)(dst + 4);
            o0.x += a0.x; o0.y += a0.y; o0.z += a0.z; o0.w += a0.w;
            o1.x += a1.x; o1.y += a1.y; o1.z += a1.z; o1.w += a1.w;
          }
          *(float4*)(dst) = o0;
          *(float4*)(dst + 4) = o1;
        }
      }
      __syncthreads();
    }
  }
}

// ---------------- gj_apply: B <- E4 E3 E2 E1 B, 8 col-stripes x 32 batches --
__global__ __launch_bounds__(256) void gj_apply(float* __restrict__ Sb,
                                                const float* __restrict__ Mtg) {
  int blk = blockIdx.x;             // 256
  int b = blk >> 3;
  int cbase = (blk & 7) * 32;
  float* Bm = Sb + ((size_t)b * 2 + 1) * 65536;
  int tid = threadIdx.x;
  int rt = tid >> 3;
  int ct = tid & 7;

  __shared__ __align__(16) float Mt[64][260];
  __shared__ __align__(8) float Bp[64][34];

  float4 breg[8];
#pragma unroll
  for (int i = 0; i < 8; ++i)
    breg[i] = *(const float4*)(Bm + (size_t)(rt * 8 + i) * 256 + cbase + ct * 4);

  for (int pg = 0; pg < 4; ++pg) {
    __syncthreads();
    {
      int j = tid >> 2, seg = (tid & 3) * 64;
      const float* src = Mtg + (((size_t)b * 4 + pg) * 64 + j) * 256 + seg;
#pragma unroll
      for (int m = 0; m < 16; ++m) {
        float4 t = *(const float4*)(src + m * 4);
        *(float4*)&Mt[j][seg + m * 4] = t;
      }
    }
    if (rt >= pg * 8 && rt < (pg + 1) * 8) {
#pragma unroll
      for (int i = 0; i < 8; ++i) {
        int j = (rt - pg * 8) * 8 + i;
        *(float2*)&Bp[j][ct * 4]     = make_float2(breg[i].x, breg[i].y);
        *(float2*)&Bp[j][ct * 4 + 2] = make_float2(breg[i].z, breg[i].w);
      }
    }
    __syncthreads();

    float acc[8][4];
#pragma unroll
    for (int i = 0; i < 8; ++i)
#pragma unroll
      for (int c = 0; c < 4; ++c) acc[i][c] = 0.f;
#pragma unroll 4
    for (int j = 0; j < 64; ++j) {
      float4 m0 = *(const float4*)&Mt[j][rt * 8];
      float4 m1 = *(const float4*)&Mt[j][rt * 8 + 4];
      float2 b0 = *(const float2*)&Bp[j][ct * 4];
      float2 b1 = *(const float2*)&Bp[j][ct * 4 + 2];
      float mv[8] = {m0.x, m0.y, m0.z, m0.w, m1.x, m1.y, m1.z, m1.w};
      float bv4[4] = {b0.x, b0.y, b1.x, b1.y};
#pragma unroll
      for (int i = 0; i < 8; ++i)
#pragma unroll
        for (int c = 0; c < 4; ++c)
          acc[i][c] = fmaf(mv[i], bv4[c], acc[i][c]);
    }
    bool inPanel = ((rt >> 3) == pg);
#pragma unroll
    for (int i = 0; i < 8; ++i) {
      if (inPanel) {
        breg[i] = make_float4(acc[i][0], acc[i][1], acc[i][2], acc[i][3]);
      } else {
        breg[i].x += acc[i][0]; breg[i].y += acc[i][1];
        breg[i].z += acc[i][2]; breg[i].w += acc[i][3];
      }
    }
  }

#pragma unroll
  for (int i = 0; i < 8; ++i)
    *(float4*)(Bm + (size_t)(rt * 8 + i) * 256 + cbase + ct * 4) = breg[i];
}

// ------- softmax_h: row stats then h[b,e] = sum_d qsum[d]*softmax(X[d,:])[e]
__global__ void softmax_h(const float* __restrict__ S,
                          const float* __restrict__ uvec,
                          float* __restrict__ out) {
  int b = blockIdx.x;
  const float* X = S + ((size_t)b * 2 + 1) * 65536;
  int tid = threadIdx.x; int lane = tid & 63; int wv = tid >> 6;
  __shared__ float mrow[256], qos[256];
  __shared__ float qs_s[256];
  qs_s[tid] = uvec[((size_t)2 * 32 + b) * DDIM + tid];
  for (int rr = 0; rr < 64; ++rr) {
    int row = rr * 4 + wv;
    float x0 = X[row * 256 + lane];
    float x1 = X[row * 256 + lane + 64];
    float x2 = X[row * 256 + lane + 128];
    float x3 = X[row * 256 + lane + 192];
    float m = fmaxf(fmaxf(x0, x1), fmaxf(x2, x3));
    for (int o = 32; o > 0; o >>= 1) m = fmaxf(m, __shfl_xor(m, o, 64));
    float s = expf(x0 - m) + expf(x1 - m) + expf(x2 - m) + expf(x3 - m);
    for (int o = 32; o > 0; o >>= 1) s += __shfl_xor(s, o, 64);
    if (lane == 0) {
      mrow[row] = m;
      qos[row] = s;
    }
  }
  __syncthreads();
  qos[tid] = qs_s[tid] / qos[tid];
  __syncthreads();
  int e = tid;
  float acc = 0.f;
  for (int d = 0; d < 256; ++d)
    acc += qos[d] * expf(X[d * 256 + e] - mrow[d]);
  out[(size_t)b * 256 + e] = acc;
}

extern "C" void kernel_launch(void* const* d_in, const int* in_sizes, int n_in,
                              void* d_out, int out_size, void* d_ws, size_t ws_size,
                              hipStream_t stream) {
  const float* q  = (const float*)d_in[0];
  const float* k  = (const float*)d_in[1];
  const float* v  = (const float*)d_in[2];
  const float* Wq = (const float*)d_in[3];
  const float* bq = (const float*)d_in[4];
  const float* Wk = (const float*)d_in[5];
  const float* bk = (const float*)d_in[6];
  const float* Wv = (const float*)d_in[7];
  const float* bv = (const float*)d_in[8];
  float* out = (float*)d_out;

  float* ws   = (float*)d_ws;
  float* Gbuf = ws;                                    // Gram partial 0; later Mtg
  float* Tbuf = Gbuf + (size_t)32 * 2 * 65536;         // [32][2][256][256]
  float* Sbuf = Tbuf + (size_t)32 * 2 * 65536;         // Gram partial 1 -> (A, B->X)
  float* part = Sbuf + (size_t)32 * 2 * 65536;         // [16][32][256] (q partials)
  float* svec = part + (size_t)16 * 3 * 32 * 256;      // [2][3][32][256]
  float* uvec = svec + (size_t)2 * 3 * 32 * 256;       // [3][32][256]

  gram_fused<<<1536, 256, 0, stream>>>(k, v, q, Gbuf, Sbuf, svec, part);
  smallvec<<<32, 256, 0, stream>>>(Wq, bq, Wk, Wv, part, svec, uvec);
  gemm_pass1<<<dim3(16, 2, 32), 256, 0, stream>>>(Wk, Gbuf, Sbuf, Tbuf);
  gemm_pass2<<<dim3(16, 2, 32), 256, 0, stream>>>(Tbuf, Wk, Wv, Sbuf, uvec, bk, bv);
  gj_factor<<<32, 1024, 0, stream>>>(Sbuf, Gbuf);
  gj_apply<<<256, 256, 0, stream>>>(Sbuf, Gbuf);
  softmax_h<<<32, 256, 0, stream>>>(Sbuf, uvec, out);
}